// Round 1
// baseline (1181.144 us; speedup 1.0000x reference)
//
#include <hip/hip_runtime.h>

// GCN 2-layer: out = Ahat( relu( Ahat(x@W1) + b1 ) @ W2 ) + b2
// Ahat = D^-1/2 (A + I) D^-1/2, push-style scatter with HW fp32 atomics.

// ---------------- small elementwise kernels ----------------

__global__ void fill_ones_k(float* __restrict__ p, int n) {
    int i = blockIdx.x * blockDim.x + threadIdx.x;
    if (i < n) p[i] = 1.0f;
}

__global__ void deg_count_k(const int* __restrict__ dst, float* __restrict__ deg, int E) {
    int i = blockIdx.x * blockDim.x + threadIdx.x;
    if (i < E) unsafeAtomicAdd(&deg[dst[i]], 1.0f);
}

__global__ void rsqrt_k(float* __restrict__ p, int n) {
    int i = blockIdx.x * blockDim.x + threadIdx.x;
    if (i < n) p[i] = rsqrtf(p[i]);   // deg >= 1 always (self-loop)
}

// o[i*D + d] = h[i*D + d] * dinv[i]^2 (+ bias[d])   — float4-vectorized
// n4 = N*D/4, shift = log2(D/4), qmask = D/4 - 1 (D is pow2)
__global__ void self_init_k(const float* __restrict__ h, const float* __restrict__ dinv,
                            const float* __restrict__ bias, float* __restrict__ o,
                            int n4, int shift, int qmask) {
    int i = blockIdx.x * blockDim.x + threadIdx.x;
    if (i >= n4) return;
    int node = i >> shift;
    float s = dinv[node];
    s *= s;
    float4 v = ((const float4*)h)[i];
    v.x *= s; v.y *= s; v.z *= s; v.w *= s;
    if (bias) {
        float4 bb = ((const float4*)bias)[i & qmask];
        v.x += bb.x; v.y += bb.y; v.z += bb.z; v.w += bb.w;
    }
    ((float4*)o)[i] = v;
}

// g = max(g + b, 0), float4-vectorized; qmask = D/4 - 1
__global__ void relu_bias_k(float* __restrict__ g, const float* __restrict__ b,
                            int n4, int qmask) {
    int i = blockIdx.x * blockDim.x + threadIdx.x;
    if (i >= n4) return;
    float4 v = ((float4*)g)[i];
    float4 bb = ((const float4*)b)[i & qmask];
    v.x = fmaxf(v.x + bb.x, 0.f);
    v.y = fmaxf(v.y + bb.y, 0.f);
    v.z = fmaxf(v.z + bb.z, 0.f);
    v.w = fmaxf(v.w + bb.w, 0.f);
    ((float4*)g)[i] = v;
}

// ---------------- fp32 GEMM, K=128 fixed, NC = 128 or 64 ----------------
// W (K x NC, row-major) staged in LDS once per block; each wave computes
// 4 rows x NC cols; lane covers NC/64 adjacent columns.
template <int NC>
__launch_bounds__(256, 2)
__global__ void gemm_k(const float* __restrict__ A, const float* __restrict__ W,
                       float* __restrict__ C, int M) {
    __shared__ float Wl[128 * NC];
    for (int i = threadIdx.x * 4; i < 128 * NC; i += 256 * 4)
        *(float4*)&Wl[i] = *(const float4*)&W[i];
    __syncthreads();

    constexpr int CPL = NC / 64;               // cols per lane (2 or 1)
    const int lane = threadIdx.x & 63;
    const int wid = (blockIdx.x << 2) + (threadIdx.x >> 6);
    const int nw = gridDim.x << 2;

    for (int r0 = wid * 4; r0 < M; r0 += nw * 4) {
        float acc[4][CPL];
#pragma unroll
        for (int r = 0; r < 4; ++r)
#pragma unroll
            for (int c = 0; c < CPL; ++c) acc[r][c] = 0.f;

        const bool full = (r0 + 4 <= M);
        float a[4][4];
#pragma unroll 1
        for (int k = 0; k < 128; k += 4) {
#pragma unroll
            for (int r = 0; r < 4; ++r) {
                if (full || r0 + r < M)
                    *(float4*)&a[r][0] = *(const float4*)&A[(size_t)(r0 + r) * 128 + k];
                else
                    a[r][0] = a[r][1] = a[r][2] = a[r][3] = 0.f;
            }
#pragma unroll
            for (int kk = 0; kk < 4; ++kk) {
                if (CPL == 2) {
                    float2 w2 = *(const float2*)&Wl[(k + kk) * NC + 2 * lane];
#pragma unroll
                    for (int r = 0; r < 4; ++r) {
                        acc[r][0] = fmaf(a[r][kk], w2.x, acc[r][0]);
                        acc[r][1] = fmaf(a[r][kk], w2.y, acc[r][1]);
                    }
                } else {
                    float wv = Wl[(k + kk) * NC + lane];
#pragma unroll
                    for (int r = 0; r < 4; ++r)
                        acc[r][0] = fmaf(a[r][kk], wv, acc[r][0]);
                }
            }
        }
#pragma unroll
        for (int r = 0; r < 4; ++r) {
            if (full || r0 + r < M) {
                if (CPL == 2) {
                    float2 st;
                    st.x = acc[r][0];
                    st.y = acc[r][1];
                    *(float2*)&C[(size_t)(r0 + r) * NC + 2 * lane] = st;
                } else {
                    C[(size_t)(r0 + r) * NC + lane] = acc[r][0];
                }
            }
        }
    }
}

// ---------------- edge scatter: one wave per edge ----------------
template <int D>
__global__ void scatter_k(const float* __restrict__ h, const int* __restrict__ src,
                          const int* __restrict__ dst, const float* __restrict__ dinv,
                          float* __restrict__ o, int E) {
    int gw = (int)((blockIdx.x * blockDim.x + threadIdx.x) >> 6);
    int lane = threadIdx.x & 63;
    if (gw >= E) return;
    int s = src[gw];
    int d = dst[gw];
    float w = dinv[s] * dinv[d];
    if (D == 128) {
        float2 v = *(const float2*)&h[(size_t)s * 128 + 2 * lane];
        unsafeAtomicAdd(&o[(size_t)d * 128 + 2 * lane], v.x * w);
        unsafeAtomicAdd(&o[(size_t)d * 128 + 2 * lane + 1], v.y * w);
    } else {
        float v = h[(size_t)s * 64 + lane];
        unsafeAtomicAdd(&o[(size_t)d * 64 + lane], v * w);
    }
}

// ---------------- launcher ----------------

extern "C" void kernel_launch(void* const* d_in, const int* in_sizes, int n_in,
                              void* d_out, int out_size, void* d_ws, size_t ws_size,
                              hipStream_t stream) {
    const float* x  = (const float*)d_in[0];
    const int*   ei = (const int*)d_in[1];
    const float* W1 = (const float*)d_in[2];
    const float* b1 = (const float*)d_in[3];
    const float* W2 = (const float*)d_in[4];
    const float* b2 = (const float*)d_in[5];
    float* out = (float*)d_out;

    const int N = in_sizes[0] / 128;
    const int E = in_sizes[1] / 2;
    const int* esrc = ei;
    const int* edst = ei + E;

    float* dinv = (float*)d_ws;                 // N
    float* h1   = dinv + N;                     // N*128 (reused as h2: N*64)
    float* g1   = h1 + (size_t)N * 128;         // N*128
    float* h2   = h1;

    const int n4_1 = N * 128 / 4;               // layer-1 float4 count
    const int n4_2 = N * 64 / 4;                // layer-2 float4 count

    // degree (with self loop) -> dinv
    hipLaunchKernelGGL(fill_ones_k, dim3((N + 255) / 256), dim3(256), 0, stream, dinv, N);
    hipLaunchKernelGGL(deg_count_k, dim3((E + 255) / 256), dim3(256), 0, stream, edst, dinv, E);
    hipLaunchKernelGGL(rsqrt_k, dim3((N + 255) / 256), dim3(256), 0, stream, dinv, N);

    // layer 1
    hipLaunchKernelGGL((gemm_k<128>), dim3(1024), dim3(256), 0, stream, x, W1, h1, N);
    hipLaunchKernelGGL(self_init_k, dim3((n4_1 + 255) / 256), dim3(256), 0, stream,
                       h1, dinv, (const float*)nullptr, g1, n4_1, 5, 31);
    hipLaunchKernelGGL((scatter_k<128>), dim3((E + 3) / 4), dim3(256), 0, stream,
                       h1, esrc, edst, dinv, g1, E);
    hipLaunchKernelGGL(relu_bias_k, dim3((n4_1 + 255) / 256), dim3(256), 0, stream,
                       g1, b1, n4_1, 31);

    // layer 2
    hipLaunchKernelGGL((gemm_k<64>), dim3(1024), dim3(256), 0, stream, g1, W2, h2, N);
    hipLaunchKernelGGL(self_init_k, dim3((n4_2 + 255) / 256), dim3(256), 0, stream,
                       h2, dinv, b2, out, n4_2, 4, 15);
    hipLaunchKernelGGL((scatter_k<64>), dim3((E + 3) / 4), dim3(256), 0, stream,
                       h2, esrc, edst, dinv, out, E);
}

// Round 2
// 508.810 us; speedup vs baseline: 2.3214x; 2.3214x over previous
//
#include <hip/hip_runtime.h>

// GCN 2-layer, pull-based: CSR by dst (counting sort) + gather, no float atomics.
// hs = (A @ W) * dinv[row]  (GEMM epilogue scale)
// out[d] = dinv[d] * (sum_{in(d)} hs[s] + hs[d]) + b   [+ relu for layer 1]

// ---------------- degree / dinv ----------------

__global__ void indeg_k(const int* __restrict__ dst, int* __restrict__ indeg, int E) {
    int i = blockIdx.x * blockDim.x + threadIdx.x;
    if (i < E) atomicAdd(&indeg[dst[i]], 1);
}

__global__ void dinv_k(const int* __restrict__ indeg, float* __restrict__ dinv, int n) {
    int i = blockIdx.x * blockDim.x + threadIdx.x;
    if (i < n) dinv[i] = rsqrtf(1.0f + (float)indeg[i]);  // +1 self-loop
}

// ---------------- exclusive scan (3-pass, 1024 elems/block) ----------------

__global__ void scan1_k(const int* __restrict__ in, int* __restrict__ out,
                        int* __restrict__ bsums, int n) {
    __shared__ int lds[256];
    int t = threadIdx.x;
    int base = blockIdx.x * 1024 + t * 4;
    int v0 = 0, v1 = 0, v2 = 0, v3 = 0;
    if (base + 0 < n) v0 = in[base + 0];
    if (base + 1 < n) v1 = in[base + 1];
    if (base + 2 < n) v2 = in[base + 2];
    if (base + 3 < n) v3 = in[base + 3];
    lds[t] = v0 + v1 + v2 + v3;
    __syncthreads();
    for (int off = 1; off < 256; off <<= 1) {
        int x = (t >= off) ? lds[t - off] : 0;
        __syncthreads();
        lds[t] += x;
        __syncthreads();
    }
    int run = (t > 0) ? lds[t - 1] : 0;
    if (t == 255) bsums[blockIdx.x] = lds[255];
    if (base + 0 < n) { out[base + 0] = run; run += v0; }
    if (base + 1 < n) { out[base + 1] = run; run += v1; }
    if (base + 2 < n) { out[base + 2] = run; run += v2; }
    if (base + 3 < n) { out[base + 3] = run; run += v3; }
}

__global__ void scan2_k(int* __restrict__ bsums, int nb) {
    if (threadIdx.x == 0 && blockIdx.x == 0) {
        int run = 0;
        for (int i = 0; i < nb; ++i) { int v = bsums[i]; bsums[i] = run; run += v; }
    }
}

__global__ void scan3_k(int* __restrict__ out, const int* __restrict__ bsums, int n) {
    int i = blockIdx.x * blockDim.x + threadIdx.x;
    if (i < n) out[i] += bsums[i >> 10];
}

// ---------------- CSR fill (row_start mutates into row_end) ----------------

__global__ void fill_k(const int* __restrict__ src, const int* __restrict__ dst,
                       int* __restrict__ cur, int* __restrict__ ssrc, int E) {
    int i = blockIdx.x * blockDim.x + threadIdx.x;
    if (i < E) {
        int d = dst[i];
        int p = atomicAdd(&cur[d], 1);
        ssrc[p] = src[i];
    }
}

// ---------------- fp32 GEMM, K=128, epilogue scale by dinv[row] ----------------

template <int NC>
__launch_bounds__(256, 2)
__global__ void gemm_k(const float* __restrict__ A, const float* __restrict__ W,
                       const float* __restrict__ dinv, float* __restrict__ C, int M) {
    __shared__ float Wl[128 * NC];
    for (int i = threadIdx.x * 4; i < 128 * NC; i += 256 * 4)
        *(float4*)&Wl[i] = *(const float4*)&W[i];
    __syncthreads();

    constexpr int CPL = NC / 64;
    const int lane = threadIdx.x & 63;
    const int wid = (blockIdx.x << 2) + (threadIdx.x >> 6);
    const int nw = gridDim.x << 2;

    for (int r0 = wid * 4; r0 < M; r0 += nw * 4) {
        float acc[4][CPL];
#pragma unroll
        for (int r = 0; r < 4; ++r)
#pragma unroll
            for (int c = 0; c < CPL; ++c) acc[r][c] = 0.f;

        const bool full = (r0 + 4 <= M);
        float a[4][4];
#pragma unroll 1
        for (int k = 0; k < 128; k += 4) {
#pragma unroll
            for (int r = 0; r < 4; ++r) {
                if (full || r0 + r < M)
                    *(float4*)&a[r][0] = *(const float4*)&A[(size_t)(r0 + r) * 128 + k];
                else
                    a[r][0] = a[r][1] = a[r][2] = a[r][3] = 0.f;
            }
#pragma unroll
            for (int kk = 0; kk < 4; ++kk) {
                if (CPL == 2) {
                    float2 w2 = *(const float2*)&Wl[(k + kk) * NC + 2 * lane];
#pragma unroll
                    for (int r = 0; r < 4; ++r) {
                        acc[r][0] = fmaf(a[r][kk], w2.x, acc[r][0]);
                        acc[r][1] = fmaf(a[r][kk], w2.y, acc[r][1]);
                    }
                } else {
                    float wv = Wl[(k + kk) * NC + lane];
#pragma unroll
                    for (int r = 0; r < 4; ++r)
                        acc[r][0] = fmaf(a[r][kk], wv, acc[r][0]);
                }
            }
        }
#pragma unroll
        for (int r = 0; r < 4; ++r) {
            if (full || r0 + r < M) {
                float s = dinv[r0 + r];
                if (CPL == 2) {
                    float2 st;
                    st.x = acc[r][0] * s;
                    st.y = acc[r][1] * s;
                    *(float2*)&C[(size_t)(r0 + r) * NC + 2 * lane] = st;
                } else {
                    C[(size_t)(r0 + r) * NC + lane] = acc[r][0] * s;
                }
            }
        }
    }
}

// ---------------- pull gather: one wave per node ----------------
// o[d] = dinv[d] * (sum_{in(d)} hs[s] + hs[d]) + bias   [+relu]

template <int D, bool RELU>
__global__ void gather_k(const float* __restrict__ hs, const int* __restrict__ ssrc,
                         const int* __restrict__ rend, const int* __restrict__ indeg,
                         const float* __restrict__ dinv, const float* __restrict__ bias,
                         float* __restrict__ o, int N) {
    int node = (int)((blockIdx.x * blockDim.x + threadIdx.x) >> 6);
    int lane = threadIdx.x & 63;
    if (node >= N) return;

    int end = rend[node];            // post-fill: row_end
    int start = end - indeg[node];
    float dv = dinv[node];

    if (D == 128) {
        const int c = 2 * lane;
        float2 acc = *(const float2*)&hs[(size_t)node * 128 + c];  // self loop
        int j = start;
        for (; j + 1 < end; j += 2) {
            int s0 = ssrc[j], s1 = ssrc[j + 1];
            float2 a = *(const float2*)&hs[(size_t)s0 * 128 + c];
            float2 b = *(const float2*)&hs[(size_t)s1 * 128 + c];
            acc.x += a.x + b.x;
            acc.y += a.y + b.y;
        }
        if (j < end) {
            int s0 = ssrc[j];
            float2 a = *(const float2*)&hs[(size_t)s0 * 128 + c];
            acc.x += a.x;
            acc.y += a.y;
        }
        float2 bb = *(const float2*)&bias[c];
        acc.x = acc.x * dv + bb.x;
        acc.y = acc.y * dv + bb.y;
        if (RELU) {
            acc.x = fmaxf(acc.x, 0.f);
            acc.y = fmaxf(acc.y, 0.f);
        }
        *(float2*)&o[(size_t)node * 128 + c] = acc;
    } else {
        float acc = hs[(size_t)node * 64 + lane];
        int j = start;
        for (; j + 1 < end; j += 2) {
            int s0 = ssrc[j], s1 = ssrc[j + 1];
            float a = hs[(size_t)s0 * 64 + lane];
            float b = hs[(size_t)s1 * 64 + lane];
            acc += a + b;
        }
        if (j < end) acc += hs[(size_t)ssrc[j] * 64 + lane];
        acc = acc * dv + bias[lane];
        if (RELU) acc = fmaxf(acc, 0.f);
        o[(size_t)node * 64 + lane] = acc;
    }
}

// ---------------- launcher ----------------

extern "C" void kernel_launch(void* const* d_in, const int* in_sizes, int n_in,
                              void* d_out, int out_size, void* d_ws, size_t ws_size,
                              hipStream_t stream) {
    const float* x  = (const float*)d_in[0];
    const int*   ei = (const int*)d_in[1];
    const float* W1 = (const float*)d_in[2];
    const float* b1 = (const float*)d_in[3];
    const float* W2 = (const float*)d_in[4];
    const float* b2 = (const float*)d_in[5];
    float* out = (float*)d_out;

    const int N = in_sizes[0] / 128;
    const int E = in_sizes[1] / 2;
    const int* esrc = ei;
    const int* edst = ei + E;

    // workspace layout
    int* indeg = (int*)d_ws;                    // N
    int* rs    = indeg + N;                     // N (row_start -> row_end after fill)
    int* bsums = rs + N;                        // 64
    int* ssrc  = bsums + 64;                    // E
    float* dinv = (float*)(ssrc + E);           // N
    float* hs1  = dinv + N;                     // N*128 (reused as hs2: N*64)
    float* g1   = hs1 + (size_t)N * 128;        // N*128
    float* hs2  = hs1;

    const int nb = (N + 1023) / 1024;

    // degree + dinv
    hipMemsetAsync(indeg, 0, (size_t)N * 4, stream);
    hipLaunchKernelGGL(indeg_k, dim3((E + 255) / 256), dim3(256), 0, stream, edst, indeg, E);
    hipLaunchKernelGGL(dinv_k, dim3((N + 255) / 256), dim3(256), 0, stream, indeg, dinv, N);

    // CSR build: exclusive scan of indeg -> rs, then fill (rs mutates to row_end)
    hipLaunchKernelGGL(scan1_k, dim3(nb), dim3(256), 0, stream, indeg, rs, bsums, N);
    hipLaunchKernelGGL(scan2_k, dim3(1), dim3(64), 0, stream, bsums, nb);
    hipLaunchKernelGGL(scan3_k, dim3((N + 255) / 256), dim3(256), 0, stream, rs, bsums, N);
    hipLaunchKernelGGL(fill_k, dim3((E + 255) / 256), dim3(256), 0, stream, esrc, edst, rs, ssrc, E);

    // layer 1: hs1 = (x@W1)*dinv ; g1 = relu(dinv*(gather+self) + b1)
    hipLaunchKernelGGL((gemm_k<128>), dim3(1024), dim3(256), 0, stream, x, W1, dinv, hs1, N);
    hipLaunchKernelGGL((gather_k<128, true>), dim3((N + 3) / 4), dim3(256), 0, stream,
                       hs1, ssrc, rs, indeg, dinv, b1, g1, N);

    // layer 2: hs2 = (g1@W2)*dinv ; out = dinv*(gather+self) + b2
    hipLaunchKernelGGL((gemm_k<64>), dim3(1024), dim3(256), 0, stream, g1, W2, dinv, hs2, N);
    hipLaunchKernelGGL((gather_k<64, false>), dim3((N + 3) / 4), dim3(256), 0, stream,
                       hs2, ssrc, rs, indeg, dinv, b2, out, N);
}